// Round 10
// baseline (1763.938 us; speedup 1.0000x reference)
//
#include <hip/hip_runtime.h>

// GNN27: two-branch diffusion GCN (N=8192, F_IN=11, F1=16, F2=32) + multi-head
// tanh-attention pooling. All fp32. Memory-bound on the two 268MB adjacencies,
// each streamed twice -> 1.07GB unique traffic -> ~170us HBM floor.
//
// R1-R6: A as <=1KB multi-streams -> 0.9-1.9 TB/s regardless of structure.
// R7/R8: 2-8KB sequential runs -> raw 3.1-3.3 TB/s, but spill / LDS-bound.
// R9: clean regs, but split-K paid the 30-shfl/row epilogue PER WINDOW and
// pv reuse was only 4 rows -> LDS-pipe-bound at 157us/dispatch (measured
// ~123us of LDS cycles). R10: full-K accumulation (epilogue ONCE, no split-K,
// no partials), 8 rows per pv b128 read (LDS reads halved), A rows as
// monotone 32KB streams, P windows staged to LDS (2 barriers/window), A
// prefetch issued right after its regs are consumed so it flies across
// barrier+staging. acc[8][16]+a[8][2] ~ 220 VGPR at launch_bounds(512,2).

constexpr int N = 8192;

// ---------------- kernel 1: P1T = (x @ W1)^T   ([16][N]) ----------------
__global__ void k_dense_in(const float* __restrict__ x0, const float* __restrict__ x1,
                           const float* __restrict__ W0, const float* __restrict__ W1,
                           float* __restrict__ o0, float* __restrict__ o1) {
    const int branch = blockIdx.y;
    const float* __restrict__ x = branch ? x1 : x0;
    const float* __restrict__ W = branch ? W1 : W0;
    float* __restrict__ o = branch ? o1 : o0;
    __shared__ float sW[11 * 16];
    if (threadIdx.x < 176) sW[threadIdx.x] = W[threadIdx.x];
    __syncthreads();
    const int n = blockIdx.x * blockDim.x + threadIdx.x;  // grid.x*256 == N exactly
    float xr[11];
#pragma unroll
    for (int j = 0; j < 11; ++j) xr[j] = x[n * 11 + j];
    float acc[16];
#pragma unroll
    for (int f = 0; f < 16; ++f) acc[f] = 0.f;
#pragma unroll
    for (int j = 0; j < 11; ++j)
#pragma unroll
        for (int f = 0; f < 16; ++f) acc[f] += xr[j] * sW[j * 16 + f];
#pragma unroll
    for (int f = 0; f < 16; ++f) o[f * N + n] = acc[f];  // transposed, coalesced
}

// ---------------- kernel 3: P2T = (H1 @ W2)^T   ([32][N]) ----------------
__global__ void k_dense_mid(const float* __restrict__ h0, const float* __restrict__ h1,
                            const float* __restrict__ W0, const float* __restrict__ W1,
                            float* __restrict__ o0, float* __restrict__ o1) {
    const int branch = blockIdx.y;
    const float* __restrict__ h = branch ? h1 : h0;
    const float* __restrict__ W = branch ? W1 : W0;
    float* __restrict__ o = branch ? o1 : o0;
    __shared__ float sW[16 * 32];
    for (int i = threadIdx.x; i < 512; i += blockDim.x) sW[i] = W[i];
    __syncthreads();
    const int n = blockIdx.x * blockDim.x + threadIdx.x;
    float hr[16];
#pragma unroll
    for (int q = 0; q < 4; ++q)
        *reinterpret_cast<float4*>(&hr[q * 4]) =
            *reinterpret_cast<const float4*>(&h[n * 16 + q * 4]);
    float acc[32];
#pragma unroll
    for (int f = 0; f < 32; ++f) acc[f] = 0.f;
#pragma unroll
    for (int j = 0; j < 16; ++j)
#pragma unroll
        for (int f = 0; f < 32; ++f) acc[f] += hr[j] * sW[j * 32 + f];
#pragma unroll
    for (int f = 0; f < 32; ++f) o[f * N + n] = acc[f];  // transposed, coalesced
}

// ---- kernels 2 & 4: H = relu(A @ P + b), full-K accumulation --------------
// Block = 512 thr = 8 waves. F=16: wave owns 8 rows, all 16 f -> 64 rows/blk.
// F=32: wave PAIR shares 8 rows; each wave owns a 16-f half -> 32 rows/blk.
// Loop over 16 K-windows of W=512: stage P window to LDS (coalesced, linear),
// barrier; compute: per chunk c (2x1KB) per f: one lane-contiguous b128 pv
// read serves 8 rows x 4 k = 32 FMAs. A rows stream as 16 sequential 2KB
// slices (monotone 32KB/row). acc[8][16] persists across windows; ONE
// shfl-compaction epilogue at the end + bias + relu + direct store.
template <int F>
__global__ __launch_bounds__(512, 2) void k_spmm(
    const float* __restrict__ A0, const float* __restrict__ A1,
    const float* __restrict__ PT0, const float* __restrict__ PT1,
    const float* __restrict__ b0, const float* __restrict__ b1,
    float* __restrict__ o0, float* __restrict__ o1,
    int ostride, int ooff) {
    constexpr int W = 512;       // K-window
    constexpr int NWIN = N / W;  // 16
    constexpr int FS = F / 16;   // f-slices per row-set: 1 | 2
    constexpr int RPB = (F == 16) ? 64 : 32;  // rows per block

    __shared__ float plds[F * W];  // 32KB | 64KB

    const int tid = threadIdx.x, lane = tid & 63, w = tid >> 6;
    const int rset = w / FS;             // row-set owner (8 | 4 sets)
    const int f0 = (w % FS) * 16;        // f-slice base
    const int br = blockIdx.y;
    const float* __restrict__ A = br ? A1 : A0;
    const float* __restrict__ PT = br ? PT1 : PT0;
    const float* __restrict__ bias = br ? b1 : b0;
    float* __restrict__ o = (br ? o1 : o0) + ooff * br;

    const int row0 = blockIdx.x * RPB + rset * 8;
    const float* __restrict__ Ab = A + (size_t)row0 * N + 4 * lane;

    float4 a[8][2];
    auto loadA = [&](int t) {
        const int K0 = t * W;
#pragma unroll
        for (int r = 0; r < 8; ++r)
#pragma unroll
            for (int c = 0; c < 2; ++c)  // c-inner: 2KB per row back-to-back
                a[r][c] = *reinterpret_cast<const float4*>(
                    Ab + (size_t)r * N + K0 + c * 256);
    };

    auto stageP = [&](int t) {
        const int K0 = t * W;
        constexpr int NF4 = F * W / 4;  // 2048 | 4096
        for (int i = tid; i < NF4; i += 512) {
            const int fl = i / (W / 4), k4 = i % (W / 4);
            *reinterpret_cast<float4*>(&plds[fl * W + 4 * k4]) =
                *reinterpret_cast<const float4*>(PT + (size_t)fl * N + K0 + 4 * k4);
        }
    };

    float acc[8][16];
#pragma unroll
    for (int r = 0; r < 8; ++r)
#pragma unroll
        for (int f = 0; f < 16; ++f) acc[r][f] = 0.f;

    loadA(0);   // flies across staging
    stageP(0);
    __syncthreads();

    for (int t = 0; t < NWIN; ++t) {
#pragma unroll
        for (int c = 0; c < 2; ++c)
#pragma unroll
            for (int f = 0; f < 16; ++f) {
                const float4 pv = *reinterpret_cast<const float4*>(
                    &plds[(f0 + f) * W + c * 256 + 4 * lane]);
#pragma unroll
                for (int r = 0; r < 8; ++r) {
                    acc[r][f] += a[r][c].x * pv.x;
                    acc[r][f] += a[r][c].y * pv.y;
                    acc[r][f] += a[r][c].z * pv.z;
                    acc[r][f] += a[r][c].w * pv.w;
                }
            }
        if (t + 1 < NWIN) loadA(t + 1);  // regs free; flies across barrier+stage
        __syncthreads();                 // all waves done reading plds
        if (t + 1 < NWIN) {
            stageP(t + 1);
            __syncthreads();
        }
    }

    // single epilogue: reduce each row over 64 k-lanes (v[16] compaction),
    // lane ends holding f = lane&15; rows in halves of 4.
    const float bv = bias[f0 + (lane & 15)];
    const int rsel = lane >> 4;
#pragma unroll
    for (int h = 0; h < 2; ++h) {
        float red[4];
#pragma unroll
        for (int r4 = 0; r4 < 4; ++r4) {
            const int r = h * 4 + r4;
            float v[16];
#pragma unroll
            for (int i = 0; i < 16; ++i) v[i] = acc[r][i];
#pragma unroll
            for (int s = 0; s < 4; ++s) {
                const int bit = (lane >> s) & 1;
#pragma unroll
                for (int i = 0; i < (16 >> s); i += 2) {
                    const float t0 = __shfl_xor(v[i], 1 << s);
                    const float t1 = __shfl_xor(v[i + 1], 1 << s);
                    v[i >> 1] = bit ? (v[i + 1] + t1) : (v[i] + t0);
                }
            }
            float rs = v[0];
            rs += __shfl_xor(rs, 16);
            rs += __shfl_xor(rs, 32);
            red[r4] = rs;
        }
        const float val = rsel == 0 ? red[0] : rsel == 1 ? red[1] : rsel == 2 ? red[2] : red[3];
        o[(size_t)(row0 + h * 4 + rsel) * ostride + f0 + (lane & 15)] =
            fmaxf(val + bv, 0.f);
    }
}

// ------- kernel 5: per-block partials of Z_h = sum e^{s}, U_h = sum e^{s}(h.Wd_h)
// tanh in [-1,1] -> softmax without max-subtraction is safe.
__global__ void k_att_pool(const float* __restrict__ h, const float* __restrict__ Watt,
                           const float* __restrict__ Wd, float* __restrict__ partials) {
    __shared__ float sWa[64 * 3];
    __shared__ float sWd[192];
    for (int i = threadIdx.x; i < 192; i += blockDim.x) {
        sWa[i] = Watt[i];
        sWd[i] = Wd[i];
    }
    __syncthreads();
    const int n = blockIdx.x * blockDim.x + threadIdx.x;  // 32*256 == N exactly
    float hv[64];
#pragma unroll
    for (int q = 0; q < 16; ++q)
        *reinterpret_cast<float4*>(&hv[q * 4]) =
            *reinterpret_cast<const float4*>(&h[(size_t)n * 64 + q * 4]);
    float s0 = 0.f, s1 = 0.f, s2 = 0.f;
#pragma unroll
    for (int d = 0; d < 64; ++d) {
        s0 += hv[d] * sWa[d * 3 + 0];
        s1 += hv[d] * sWa[d * 3 + 1];
        s2 += hv[d] * sWa[d * 3 + 2];
    }
    float dot0 = 0.f, dot1 = 0.f, dot2 = 0.f;
#pragma unroll
    for (int d = 0; d < 64; ++d) {
        dot0 += hv[d] * sWd[0 * 64 + d];
        dot1 += hv[d] * sWd[1 * 64 + d];
        dot2 += hv[d] * sWd[2 * 64 + d];
    }
    const float e0 = expf(tanhf(s0));
    const float e1 = expf(tanhf(s1));
    const float e2 = expf(tanhf(s2));
    float vals[6] = {e0, e1, e2, e0 * dot0, e1 * dot1, e2 * dot2};
#pragma unroll
    for (int i = 0; i < 6; ++i) {
        float v = vals[i];
#pragma unroll
        for (int off = 1; off < 64; off <<= 1) v += __shfl_xor(v, off);
        vals[i] = v;
    }
    __shared__ float sred[4][6];
    const int wave = threadIdx.x >> 6, lane = threadIdx.x & 63;
    if (lane == 0) {
#pragma unroll
        for (int i = 0; i < 6; ++i) sred[wave][i] = vals[i];
    }
    __syncthreads();
    if (threadIdx.x == 0) {
#pragma unroll
        for (int i = 0; i < 6; ++i)
            partials[blockIdx.x * 6 + i] = sred[0][i] + sred[1][i] + sred[2][i] + sred[3][i];
    }
}

// ------------- kernel 6: out = sum_h U_h/Z_h + b_dense -------------
__global__ void k_att_final(const float* __restrict__ partials, const float* __restrict__ bd,
                            float* __restrict__ out) {
    if (threadIdx.x == 0) {
        float Z0 = 0.f, Z1 = 0.f, Z2 = 0.f, U0 = 0.f, U1 = 0.f, U2 = 0.f;
        for (int b = 0; b < 32; ++b) {
            Z0 += partials[b * 6 + 0];
            Z1 += partials[b * 6 + 1];
            Z2 += partials[b * 6 + 2];
            U0 += partials[b * 6 + 3];
            U1 += partials[b * 6 + 4];
            U2 += partials[b * 6 + 5];
        }
        out[0] = U0 / Z0 + U1 / Z1 + U2 / Z2 + bd[0];
    }
}

extern "C" void kernel_launch(void* const* d_in, const int* in_sizes, int n_in,
                              void* d_out, int out_size, void* d_ws, size_t ws_size,
                              hipStream_t stream) {
    const float* x_int   = (const float*)d_in[0];
    const float* x_nh    = (const float*)d_in[1];
    const float* adj_int = (const float*)d_in[2];
    const float* adj_nh  = (const float*)d_in[3];
    const float* W1_int  = (const float*)d_in[4];
    const float* b1_int  = (const float*)d_in[5];
    const float* W1_nh   = (const float*)d_in[6];
    const float* b1_nh   = (const float*)d_in[7];
    const float* W2_int  = (const float*)d_in[8];
    const float* b2_int  = (const float*)d_in[9];
    const float* W2_nh   = (const float*)d_in[10];
    const float* b2_nh   = (const float*)d_in[11];
    const float* W_att   = (const float*)d_in[12];
    const float* W_dense = (const float*)d_in[13];
    const float* b_dense = (const float*)d_in[14];

    float* ws = (float*)d_ws;
    float* P1T_0 = ws;                       // [16][8192]
    float* P1T_1 = ws + 131072;
    float* H1_0  = ws + 262144;              // [8192][16] row-major
    float* H1_1  = ws + 393216;
    float* P2T_0 = ws + 524288;              // [32][8192]
    float* P2T_1 = ws + 786432;
    float* hcat  = ws + 1048576;             // [8192][64] = [H2_int | H2_nh]
    float* attp  = ws + 1572864;             // [32,6]
    float* out = (float*)d_out;

    k_dense_in<<<dim3(32, 2), 256, 0, stream>>>(x_int, x_nh, W1_int, W1_nh, P1T_0, P1T_1);
    // layer 1: F=16, 64 rows/block -> 128 blocks x 2 branches
    k_spmm<16><<<dim3(128, 2), 512, 0, stream>>>(adj_int, adj_nh, P1T_0, P1T_1,
                                                 b1_int, b1_nh, H1_0, H1_1, 16, 0);
    k_dense_mid<<<dim3(32, 2), 256, 0, stream>>>(H1_0, H1_1, W2_int, W2_nh, P2T_0, P2T_1);
    // layer 2: F=32, 32 rows/block -> 256 blocks x 2 branches; both branches
    // write into hcat ([.,0:32] int, [.,32:64] nh)
    k_spmm<32><<<dim3(256, 2), 512, 0, stream>>>(adj_int, adj_nh, P2T_0, P2T_1,
                                                 b2_int, b2_nh, hcat, hcat, 64, 32);
    k_att_pool<<<32, 256, 0, stream>>>(hcat, W_att, W_dense, attp);
    k_att_final<<<1, 64, 0, stream>>>(attp, b_dense, out);
}

// Round 11
// 1760.689 us; speedup vs baseline: 1.0018x; 1.0018x over previous
//
#include <hip/hip_runtime.h>

// GNN27: two-branch diffusion GCN (N=8192, F_IN=11, F1=16, F2=32) + multi-head
// tanh-attention pooling. All fp32. Memory-bound on the two 268MB adjacencies,
// each streamed twice -> 1.07GB unique traffic -> ~170us HBM floor.
//
// R1-R6: A as <=1KB multi-streams -> 0.9-1.9 TB/s. R7/R8: long sequential
// runs -> raw 3.1-3.6 TB/s proven, but spilled / LDS-bound. R9: clean regs,
// split-K epilogue 16x + 4-row reuse -> LDS-pipe-bound. R10: full-K + 8-row
// reuse was RIGHT but __launch_bounds__(512,2) = 2 waves/SIMD = 128-VGPR cap
// -> acc[8][16] spilled (2.4GB scratch @ 3.6 TB/s). R11: launch_bounds(512,1)
// -> 256-VGPR budget, 1 block/CU (8 waves = 2/SIMD, 16KB A in flight per
// wave >> 10KB latency-BW product). Same structure: 16 K-windows of W=512,
// P window staged to LDS (linear, conflict-free), per pv b128 read 8 rows x
// 4 k = 32 FMAs, monotone 32KB/row A streams, ONE shfl epilogue.

constexpr int N = 8192;

// ---------------- kernel 1: P1T = (x @ W1)^T   ([16][N]) ----------------
__global__ void k_dense_in(const float* __restrict__ x0, const float* __restrict__ x1,
                           const float* __restrict__ W0, const float* __restrict__ W1,
                           float* __restrict__ o0, float* __restrict__ o1) {
    const int branch = blockIdx.y;
    const float* __restrict__ x = branch ? x1 : x0;
    const float* __restrict__ W = branch ? W1 : W0;
    float* __restrict__ o = branch ? o1 : o0;
    __shared__ float sW[11 * 16];
    if (threadIdx.x < 176) sW[threadIdx.x] = W[threadIdx.x];
    __syncthreads();
    const int n = blockIdx.x * blockDim.x + threadIdx.x;  // grid.x*256 == N exactly
    float xr[11];
#pragma unroll
    for (int j = 0; j < 11; ++j) xr[j] = x[n * 11 + j];
    float acc[16];
#pragma unroll
    for (int f = 0; f < 16; ++f) acc[f] = 0.f;
#pragma unroll
    for (int j = 0; j < 11; ++j)
#pragma unroll
        for (int f = 0; f < 16; ++f) acc[f] += xr[j] * sW[j * 16 + f];
#pragma unroll
    for (int f = 0; f < 16; ++f) o[f * N + n] = acc[f];  // transposed, coalesced
}

// ---------------- kernel 3: P2T = (H1 @ W2)^T   ([32][N]) ----------------
__global__ void k_dense_mid(const float* __restrict__ h0, const float* __restrict__ h1,
                            const float* __restrict__ W0, const float* __restrict__ W1,
                            float* __restrict__ o0, float* __restrict__ o1) {
    const int branch = blockIdx.y;
    const float* __restrict__ h = branch ? h1 : h0;
    const float* __restrict__ W = branch ? W1 : W0;
    float* __restrict__ o = branch ? o1 : o0;
    __shared__ float sW[16 * 32];
    for (int i = threadIdx.x; i < 512; i += blockDim.x) sW[i] = W[i];
    __syncthreads();
    const int n = blockIdx.x * blockDim.x + threadIdx.x;
    float hr[16];
#pragma unroll
    for (int q = 0; q < 4; ++q)
        *reinterpret_cast<float4*>(&hr[q * 4]) =
            *reinterpret_cast<const float4*>(&h[n * 16 + q * 4]);
    float acc[32];
#pragma unroll
    for (int f = 0; f < 32; ++f) acc[f] = 0.f;
#pragma unroll
    for (int j = 0; j < 16; ++j)
#pragma unroll
        for (int f = 0; f < 32; ++f) acc[f] += hr[j] * sW[j * 32 + f];
#pragma unroll
    for (int f = 0; f < 32; ++f) o[f * N + n] = acc[f];  // transposed, coalesced
}

// ---- kernels 2 & 4: H = relu(A @ P + b), full-K accumulation --------------
// Block = 512 thr = 8 waves, 1 block/CU (256-VGPR budget). F=16: wave owns
// 8 rows, all 16 f -> 64 rows/blk. F=32: wave PAIR shares 8 rows; each wave
// owns a 16-f half -> 32 rows/blk (L1 absorbs the duplicate A reads).
// Loop over 16 K-windows of W=512: stage P window to LDS (coalesced, linear),
// barrier; compute: per chunk c (2x1KB) per f: one lane-contiguous b128 pv
// read serves 8 rows x 4 k = 32 FMAs. A rows stream as 16 sequential 2KB
// slices (monotone 32KB/row). acc[8][16] persists; ONE shfl epilogue.
template <int F>
__global__ __launch_bounds__(512, 1) void k_spmm(
    const float* __restrict__ A0, const float* __restrict__ A1,
    const float* __restrict__ PT0, const float* __restrict__ PT1,
    const float* __restrict__ b0, const float* __restrict__ b1,
    float* __restrict__ o0, float* __restrict__ o1,
    int ostride, int ooff) {
    constexpr int W = 512;       // K-window
    constexpr int NWIN = N / W;  // 16
    constexpr int FS = F / 16;   // f-slices per row-set: 1 | 2
    constexpr int RPB = (F == 16) ? 64 : 32;  // rows per block

    __shared__ float plds[F * W];  // 32KB | 64KB

    const int tid = threadIdx.x, lane = tid & 63, w = tid >> 6;
    const int rset = w / FS;             // row-set owner (8 | 4 sets)
    const int f0 = (w % FS) * 16;        // f-slice base
    const int br = blockIdx.y;
    const float* __restrict__ A = br ? A1 : A0;
    const float* __restrict__ PT = br ? PT1 : PT0;
    const float* __restrict__ bias = br ? b1 : b0;
    float* __restrict__ o = (br ? o1 : o0) + ooff * br;

    const int row0 = blockIdx.x * RPB + rset * 8;
    const float* __restrict__ Ab = A + (size_t)row0 * N + 4 * lane;

    float4 a[8][2];
    auto loadA = [&](int t) {
        const int K0 = t * W;
#pragma unroll
        for (int r = 0; r < 8; ++r)
#pragma unroll
            for (int c = 0; c < 2; ++c)  // c-inner: 2KB per row back-to-back
                a[r][c] = *reinterpret_cast<const float4*>(
                    Ab + (size_t)r * N + K0 + c * 256);
    };

    auto stageP = [&](int t) {
        const int K0 = t * W;
        constexpr int NF4 = F * W / 4;  // 2048 | 4096
        for (int i = tid; i < NF4; i += 512) {
            const int fl = i / (W / 4), k4 = i % (W / 4);
            *reinterpret_cast<float4*>(&plds[fl * W + 4 * k4]) =
                *reinterpret_cast<const float4*>(PT + (size_t)fl * N + K0 + 4 * k4);
        }
    };

    float acc[8][16];
#pragma unroll
    for (int r = 0; r < 8; ++r)
#pragma unroll
        for (int f = 0; f < 16; ++f) acc[r][f] = 0.f;

    loadA(0);   // flies across staging
    stageP(0);
    __syncthreads();

    for (int t = 0; t < NWIN; ++t) {
#pragma unroll
        for (int c = 0; c < 2; ++c)
#pragma unroll
            for (int f = 0; f < 16; ++f) {
                const float4 pv = *reinterpret_cast<const float4*>(
                    &plds[(f0 + f) * W + c * 256 + 4 * lane]);
#pragma unroll
                for (int r = 0; r < 8; ++r) {
                    acc[r][f] += a[r][c].x * pv.x;
                    acc[r][f] += a[r][c].y * pv.y;
                    acc[r][f] += a[r][c].z * pv.z;
                    acc[r][f] += a[r][c].w * pv.w;
                }
            }
        if (t + 1 < NWIN) loadA(t + 1);  // regs free; flies across barrier+stage
        __syncthreads();                 // all waves done reading plds
        if (t + 1 < NWIN) {
            stageP(t + 1);
            __syncthreads();
        }
    }

    // single epilogue: reduce each row over 64 k-lanes (v[16] compaction),
    // lane ends holding f = lane&15; rows in halves of 4.
    const float bv = bias[f0 + (lane & 15)];
    const int rsel = lane >> 4;
#pragma unroll
    for (int h = 0; h < 2; ++h) {
        float red[4];
#pragma unroll
        for (int r4 = 0; r4 < 4; ++r4) {
            const int r = h * 4 + r4;
            float v[16];
#pragma unroll
            for (int i = 0; i < 16; ++i) v[i] = acc[r][i];
#pragma unroll
            for (int s = 0; s < 4; ++s) {
                const int bit = (lane >> s) & 1;
#pragma unroll
                for (int i = 0; i < (16 >> s); i += 2) {
                    const float t0 = __shfl_xor(v[i], 1 << s);
                    const float t1 = __shfl_xor(v[i + 1], 1 << s);
                    v[i >> 1] = bit ? (v[i + 1] + t1) : (v[i] + t0);
                }
            }
            float rs = v[0];
            rs += __shfl_xor(rs, 16);
            rs += __shfl_xor(rs, 32);
            red[r4] = rs;
        }
        const float val = rsel == 0 ? red[0] : rsel == 1 ? red[1] : rsel == 2 ? red[2] : red[3];
        o[(size_t)(row0 + h * 4 + rsel) * ostride + f0 + (lane & 15)] =
            fmaxf(val + bv, 0.f);
    }
}

// ------- kernel 5: per-block partials of Z_h = sum e^{s}, U_h = sum e^{s}(h.Wd_h)
// tanh in [-1,1] -> softmax without max-subtraction is safe.
__global__ void k_att_pool(const float* __restrict__ h, const float* __restrict__ Watt,
                           const float* __restrict__ Wd, float* __restrict__ partials) {
    __shared__ float sWa[64 * 3];
    __shared__ float sWd[192];
    for (int i = threadIdx.x; i < 192; i += blockDim.x) {
        sWa[i] = Watt[i];
        sWd[i] = Wd[i];
    }
    __syncthreads();
    const int n = blockIdx.x * blockDim.x + threadIdx.x;  // 32*256 == N exactly
    float hv[64];
#pragma unroll
    for (int q = 0; q < 16; ++q)
        *reinterpret_cast<float4*>(&hv[q * 4]) =
            *reinterpret_cast<const float4*>(&h[(size_t)n * 64 + q * 4]);
    float s0 = 0.f, s1 = 0.f, s2 = 0.f;
#pragma unroll
    for (int d = 0; d < 64; ++d) {
        s0 += hv[d] * sWa[d * 3 + 0];
        s1 += hv[d] * sWa[d * 3 + 1];
        s2 += hv[d] * sWa[d * 3 + 2];
    }
    float dot0 = 0.f, dot1 = 0.f, dot2 = 0.f;
#pragma unroll
    for (int d = 0; d < 64; ++d) {
        dot0 += hv[d] * sWd[0 * 64 + d];
        dot1 += hv[d] * sWd[1 * 64 + d];
        dot2 += hv[d] * sWd[2 * 64 + d];
    }
    const float e0 = expf(tanhf(s0));
    const float e1 = expf(tanhf(s1));
    const float e2 = expf(tanhf(s2));
    float vals[6] = {e0, e1, e2, e0 * dot0, e1 * dot1, e2 * dot2};
#pragma unroll
    for (int i = 0; i < 6; ++i) {
        float v = vals[i];
#pragma unroll
        for (int off = 1; off < 64; off <<= 1) v += __shfl_xor(v, off);
        vals[i] = v;
    }
    __shared__ float sred[4][6];
    const int wave = threadIdx.x >> 6, lane = threadIdx.x & 63;
    if (lane == 0) {
#pragma unroll
        for (int i = 0; i < 6; ++i) sred[wave][i] = vals[i];
    }
    __syncthreads();
    if (threadIdx.x == 0) {
#pragma unroll
        for (int i = 0; i < 6; ++i)
            partials[blockIdx.x * 6 + i] = sred[0][i] + sred[1][i] + sred[2][i] + sred[3][i];
    }
}

// ------------- kernel 6: out = sum_h U_h/Z_h + b_dense -------------
__global__ void k_att_final(const float* __restrict__ partials, const float* __restrict__ bd,
                            float* __restrict__ out) {
    if (threadIdx.x == 0) {
        float Z0 = 0.f, Z1 = 0.f, Z2 = 0.f, U0 = 0.f, U1 = 0.f, U2 = 0.f;
        for (int b = 0; b < 32; ++b) {
            Z0 += partials[b * 6 + 0];
            Z1 += partials[b * 6 + 1];
            Z2 += partials[b * 6 + 2];
            U0 += partials[b * 6 + 3];
            U1 += partials[b * 6 + 4];
            U2 += partials[b * 6 + 5];
        }
        out[0] = U0 / Z0 + U1 / Z1 + U2 / Z2 + bd[0];
    }
}

extern "C" void kernel_launch(void* const* d_in, const int* in_sizes, int n_in,
                              void* d_out, int out_size, void* d_ws, size_t ws_size,
                              hipStream_t stream) {
    const float* x_int   = (const float*)d_in[0];
    const float* x_nh    = (const float*)d_in[1];
    const float* adj_int = (const float*)d_in[2];
    const float* adj_nh  = (const float*)d_in[3];
    const float* W1_int  = (const float*)d_in[4];
    const float* b1_int  = (const float*)d_in[5];
    const float* W1_nh   = (const float*)d_in[6];
    const float* b1_nh   = (const float*)d_in[7];
    const float* W2_int  = (const float*)d_in[8];
    const float* b2_int  = (const float*)d_in[9];
    const float* W2_nh   = (const float*)d_in[10];
    const float* b2_nh   = (const float*)d_in[11];
    const float* W_att   = (const float*)d_in[12];
    const float* W_dense = (const float*)d_in[13];
    const float* b_dense = (const float*)d_in[14];

    float* ws = (float*)d_ws;
    float* P1T_0 = ws;                       // [16][8192]
    float* P1T_1 = ws + 131072;
    float* H1_0  = ws + 262144;              // [8192][16] row-major
    float* H1_1  = ws + 393216;
    float* P2T_0 = ws + 524288;              // [32][8192]
    float* P2T_1 = ws + 786432;
    float* hcat  = ws + 1048576;             // [8192][64] = [H2_int | H2_nh]
    float* attp  = ws + 1572864;             // [32,6]
    float* out = (float*)d_out;

    k_dense_in<<<dim3(32, 2), 256, 0, stream>>>(x_int, x_nh, W1_int, W1_nh, P1T_0, P1T_1);
    // layer 1: F=16, 64 rows/block -> 128 blocks x 2 branches = 256 = 1/CU
    k_spmm<16><<<dim3(128, 2), 512, 0, stream>>>(adj_int, adj_nh, P1T_0, P1T_1,
                                                 b1_int, b1_nh, H1_0, H1_1, 16, 0);
    k_dense_mid<<<dim3(32, 2), 256, 0, stream>>>(H1_0, H1_1, W2_int, W2_nh, P2T_0, P2T_1);
    // layer 2: F=32, 32 rows/block -> 256 blocks x 2 branches; both branches
    // write into hcat ([.,0:32] int, [.,32:64] nh)
    k_spmm<32><<<dim3(256, 2), 512, 0, stream>>>(adj_int, adj_nh, P2T_0, P2T_1,
                                                 b2_int, b2_nh, hcat, hcat, 64, 32);
    k_att_pool<<<32, 256, 0, stream>>>(hcat, W_att, W_dense, attp);
    k_att_final<<<1, 64, 0, stream>>>(attp, b_dense, out);
}

// Round 12
// 812.739 us; speedup vs baseline: 2.1704x; 2.1664x over previous
//
#include <hip/hip_runtime.h>

// GNN27: two-branch diffusion GCN (N=8192, F_IN=11, F1=16, F2=32) + multi-head
// tanh-attention pooling. All fp32. Memory-bound on the two 268MB adjacencies,
// each streamed twice -> 1.07GB unique traffic -> ~170us HBM floor.
//
// R1-R6: A as <=1KB multi-streams -> 0.9-1.9 TB/s. R7/R8: long sequential
// runs -> raw 3.1-3.6 TB/s proven. R9: 4-row/wave footprint compiles CLEAN
// at the 128-VGPR cap (no scratch) but split-K paid the epilogue 16x ->
// LDS-bound. R10/R11: 8-row full-K spilled; launch_bounds(512,1) did NOT
// raise the 128-reg allocation (counters identical) -> don't fight the cap.
// R12: full-K accumulation at the PROVEN footprint: 4 rows/wave, acc[4][16]
// + a[4][2] ~ 120 VGPR, ONE shfl epilogue, no partials. W=512 P windows in
// LDS (linear, conflict-free); A rows stream monotone 32KB. 2 blocks/CU.
// Per-CU arithmetic: HBM 2.1MB ~ 85us floor; VALU ~54us; LDS ~41us.

constexpr int N = 8192;

// ---------------- kernel 1: P1T = (x @ W1)^T   ([16][N]) ----------------
__global__ void k_dense_in(const float* __restrict__ x0, const float* __restrict__ x1,
                           const float* __restrict__ W0, const float* __restrict__ W1,
                           float* __restrict__ o0, float* __restrict__ o1) {
    const int branch = blockIdx.y;
    const float* __restrict__ x = branch ? x1 : x0;
    const float* __restrict__ W = branch ? W1 : W0;
    float* __restrict__ o = branch ? o1 : o0;
    __shared__ float sW[11 * 16];
    if (threadIdx.x < 176) sW[threadIdx.x] = W[threadIdx.x];
    __syncthreads();
    const int n = blockIdx.x * blockDim.x + threadIdx.x;  // grid.x*256 == N exactly
    float xr[11];
#pragma unroll
    for (int j = 0; j < 11; ++j) xr[j] = x[n * 11 + j];
    float acc[16];
#pragma unroll
    for (int f = 0; f < 16; ++f) acc[f] = 0.f;
#pragma unroll
    for (int j = 0; j < 11; ++j)
#pragma unroll
        for (int f = 0; f < 16; ++f) acc[f] += xr[j] * sW[j * 16 + f];
#pragma unroll
    for (int f = 0; f < 16; ++f) o[f * N + n] = acc[f];  // transposed, coalesced
}

// ---------------- kernel 3: P2T = (H1 @ W2)^T   ([32][N]) ----------------
__global__ void k_dense_mid(const float* __restrict__ h0, const float* __restrict__ h1,
                            const float* __restrict__ W0, const float* __restrict__ W1,
                            float* __restrict__ o0, float* __restrict__ o1) {
    const int branch = blockIdx.y;
    const float* __restrict__ h = branch ? h1 : h0;
    const float* __restrict__ W = branch ? W1 : W0;
    float* __restrict__ o = branch ? o1 : o0;
    __shared__ float sW[16 * 32];
    for (int i = threadIdx.x; i < 512; i += blockDim.x) sW[i] = W[i];
    __syncthreads();
    const int n = blockIdx.x * blockDim.x + threadIdx.x;
    float hr[16];
#pragma unroll
    for (int q = 0; q < 4; ++q)
        *reinterpret_cast<float4*>(&hr[q * 4]) =
            *reinterpret_cast<const float4*>(&h[n * 16 + q * 4]);
    float acc[32];
#pragma unroll
    for (int f = 0; f < 32; ++f) acc[f] = 0.f;
#pragma unroll
    for (int j = 0; j < 16; ++j)
#pragma unroll
        for (int f = 0; f < 32; ++f) acc[f] += hr[j] * sW[j * 32 + f];
#pragma unroll
    for (int f = 0; f < 32; ++f) o[f * N + n] = acc[f];  // transposed, coalesced
}

// ---- kernels 2 & 4: H = relu(A @ P + b), full-K acc, 4 rows/wave ----------
// Block = 512 thr = 8 waves. F=16: wave owns 4 rows, all 16 f -> 32 rows/blk.
// F=32: wave PAIR shares 4 rows; each wave owns a 16-f half -> 16 rows/blk
// (L1 absorbs duplicate A reads). Loop over 16 K-windows of W=512: stage P
// window to LDS (coalesced, linear, conflict-free), barrier; per chunk c
// (2x1KB) per f: one lane-contiguous b128 pv read serves 4 rows x 4 k =
// 16 FMAs. A rows stream as 16 sequential 2KB slices (monotone 32KB/row);
// next window's A issued right after regs are consumed (flies across
// barrier+staging). acc[4][16] persists; ONE shfl epilogue + bias + relu.
template <int F>
__global__ __launch_bounds__(512, 2) void k_spmm(
    const float* __restrict__ A0, const float* __restrict__ A1,
    const float* __restrict__ PT0, const float* __restrict__ PT1,
    const float* __restrict__ b0, const float* __restrict__ b1,
    float* __restrict__ o0, float* __restrict__ o1,
    int ostride, int ooff) {
    constexpr int W = 512;       // K-window
    constexpr int NWIN = N / W;  // 16
    constexpr int FS = F / 16;   // f-slices per row-set: 1 | 2
    constexpr int RPB = (F == 16) ? 32 : 16;  // rows per block

    __shared__ float plds[F * W];  // 32KB | 64KB

    const int tid = threadIdx.x, lane = tid & 63, w = tid >> 6;
    const int rset = w / FS;             // row-set owner (8 | 4 sets)
    const int f0 = (w % FS) * 16;        // f-slice base
    const int br = blockIdx.y;
    const float* __restrict__ A = br ? A1 : A0;
    const float* __restrict__ PT = br ? PT1 : PT0;
    const float* __restrict__ bias = br ? b1 : b0;
    float* __restrict__ o = (br ? o1 : o0) + ooff * br;

    const int row0 = blockIdx.x * RPB + rset * 4;
    const float* __restrict__ Ab = A + (size_t)row0 * N + 4 * lane;

    float4 a[4][2];
    auto loadA = [&](int t) {
        const int K0 = t * W;
#pragma unroll
        for (int r = 0; r < 4; ++r)
#pragma unroll
            for (int c = 0; c < 2; ++c)  // c-inner: 2KB per row back-to-back
                a[r][c] = *reinterpret_cast<const float4*>(
                    Ab + (size_t)r * N + K0 + c * 256);
    };

    auto stageP = [&](int t) {
        const int K0 = t * W;
        constexpr int NF4 = F * W / 4;  // 2048 | 4096
        for (int i = tid; i < NF4; i += 512) {
            const int fl = i / (W / 4), k4 = i % (W / 4);
            *reinterpret_cast<float4*>(&plds[fl * W + 4 * k4]) =
                *reinterpret_cast<const float4*>(PT + (size_t)fl * N + K0 + 4 * k4);
        }
    };

    float acc[4][16];
#pragma unroll
    for (int r = 0; r < 4; ++r)
#pragma unroll
        for (int f = 0; f < 16; ++f) acc[r][f] = 0.f;

    loadA(0);   // flies across staging
    stageP(0);
    __syncthreads();

    for (int t = 0; t < NWIN; ++t) {
#pragma unroll
        for (int c = 0; c < 2; ++c)
#pragma unroll
            for (int f = 0; f < 16; ++f) {
                const float4 pv = *reinterpret_cast<const float4*>(
                    &plds[(f0 + f) * W + c * 256 + 4 * lane]);
#pragma unroll
                for (int r = 0; r < 4; ++r) {
                    acc[r][f] += a[r][c].x * pv.x;
                    acc[r][f] += a[r][c].y * pv.y;
                    acc[r][f] += a[r][c].z * pv.z;
                    acc[r][f] += a[r][c].w * pv.w;
                }
            }
        if (t + 1 < NWIN) loadA(t + 1);  // regs free; flies across barrier+stage
        __syncthreads();                 // all waves done reading plds
        if (t + 1 < NWIN) {
            stageP(t + 1);
            __syncthreads();
        }
    }

    // single epilogue: reduce each of the 4 rows over 64 k-lanes (v[16]
    // compaction); lane ends holding row = lane>>4, f = lane&15.
    const float bv = bias[f0 + (lane & 15)];
    const int rsel = lane >> 4;
    float red[4];
#pragma unroll
    for (int r = 0; r < 4; ++r) {
        float v[16];
#pragma unroll
        for (int i = 0; i < 16; ++i) v[i] = acc[r][i];
#pragma unroll
        for (int s = 0; s < 4; ++s) {
            const int bit = (lane >> s) & 1;
#pragma unroll
            for (int i = 0; i < (16 >> s); i += 2) {
                const float t0 = __shfl_xor(v[i], 1 << s);
                const float t1 = __shfl_xor(v[i + 1], 1 << s);
                v[i >> 1] = bit ? (v[i + 1] + t1) : (v[i] + t0);
            }
        }
        float rs = v[0];
        rs += __shfl_xor(rs, 16);
        rs += __shfl_xor(rs, 32);
        red[r] = rs;
    }
    const float val = rsel == 0 ? red[0] : rsel == 1 ? red[1] : rsel == 2 ? red[2] : red[3];
    o[(size_t)(row0 + rsel) * ostride + f0 + (lane & 15)] = fmaxf(val + bv, 0.f);
}

// ------- kernel 5: per-block partials of Z_h = sum e^{s}, U_h = sum e^{s}(h.Wd_h)
// tanh in [-1,1] -> softmax without max-subtraction is safe.
__global__ void k_att_pool(const float* __restrict__ h, const float* __restrict__ Watt,
                           const float* __restrict__ Wd, float* __restrict__ partials) {
    __shared__ float sWa[64 * 3];
    __shared__ float sWd[192];
    for (int i = threadIdx.x; i < 192; i += blockDim.x) {
        sWa[i] = Watt[i];
        sWd[i] = Wd[i];
    }
    __syncthreads();
    const int n = blockIdx.x * blockDim.x + threadIdx.x;  // 32*256 == N exactly
    float hv[64];
#pragma unroll
    for (int q = 0; q < 16; ++q)
        *reinterpret_cast<float4*>(&hv[q * 4]) =
            *reinterpret_cast<const float4*>(&h[(size_t)n * 64 + q * 4]);
    float s0 = 0.f, s1 = 0.f, s2 = 0.f;
#pragma unroll
    for (int d = 0; d < 64; ++d) {
        s0 += hv[d] * sWa[d * 3 + 0];
        s1 += hv[d] * sWa[d * 3 + 1];
        s2 += hv[d] * sWa[d * 3 + 2];
    }
    float dot0 = 0.f, dot1 = 0.f, dot2 = 0.f;
#pragma unroll
    for (int d = 0; d < 64; ++d) {
        dot0 += hv[d] * sWd[0 * 64 + d];
        dot1 += hv[d] * sWd[1 * 64 + d];
        dot2 += hv[d] * sWd[2 * 64 + d];
    }
    const float e0 = expf(tanhf(s0));
    const float e1 = expf(tanhf(s1));
    const float e2 = expf(tanhf(s2));
    float vals[6] = {e0, e1, e2, e0 * dot0, e1 * dot1, e2 * dot2};
#pragma unroll
    for (int i = 0; i < 6; ++i) {
        float v = vals[i];
#pragma unroll
        for (int off = 1; off < 64; off <<= 1) v += __shfl_xor(v, off);
        vals[i] = v;
    }
    __shared__ float sred[4][6];
    const int wave = threadIdx.x >> 6, lane = threadIdx.x & 63;
    if (lane == 0) {
#pragma unroll
        for (int i = 0; i < 6; ++i) sred[wave][i] = vals[i];
    }
    __syncthreads();
    if (threadIdx.x == 0) {
#pragma unroll
        for (int i = 0; i < 6; ++i)
            partials[blockIdx.x * 6 + i] = sred[0][i] + sred[1][i] + sred[2][i] + sred[3][i];
    }
}

// ------------- kernel 6: out = sum_h U_h/Z_h + b_dense -------------
__global__ void k_att_final(const float* __restrict__ partials, const float* __restrict__ bd,
                            float* __restrict__ out) {
    if (threadIdx.x == 0) {
        float Z0 = 0.f, Z1 = 0.f, Z2 = 0.f, U0 = 0.f, U1 = 0.f, U2 = 0.f;
        for (int b = 0; b < 32; ++b) {
            Z0 += partials[b * 6 + 0];
            Z1 += partials[b * 6 + 1];
            Z2 += partials[b * 6 + 2];
            U0 += partials[b * 6 + 3];
            U1 += partials[b * 6 + 4];
            U2 += partials[b * 6 + 5];
        }
        out[0] = U0 / Z0 + U1 / Z1 + U2 / Z2 + bd[0];
    }
}

extern "C" void kernel_launch(void* const* d_in, const int* in_sizes, int n_in,
                              void* d_out, int out_size, void* d_ws, size_t ws_size,
                              hipStream_t stream) {
    const float* x_int   = (const float*)d_in[0];
    const float* x_nh    = (const float*)d_in[1];
    const float* adj_int = (const float*)d_in[2];
    const float* adj_nh  = (const float*)d_in[3];
    const float* W1_int  = (const float*)d_in[4];
    const float* b1_int  = (const float*)d_in[5];
    const float* W1_nh   = (const float*)d_in[6];
    const float* b1_nh   = (const float*)d_in[7];
    const float* W2_int  = (const float*)d_in[8];
    const float* b2_int  = (const float*)d_in[9];
    const float* W2_nh   = (const float*)d_in[10];
    const float* b2_nh   = (const float*)d_in[11];
    const float* W_att   = (const float*)d_in[12];
    const float* W_dense = (const float*)d_in[13];
    const float* b_dense = (const float*)d_in[14];

    float* ws = (float*)d_ws;
    float* P1T_0 = ws;                       // [16][8192]
    float* P1T_1 = ws + 131072;
    float* H1_0  = ws + 262144;              // [8192][16] row-major
    float* H1_1  = ws + 393216;
    float* P2T_0 = ws + 524288;              // [32][8192]
    float* P2T_1 = ws + 786432;
    float* hcat  = ws + 1048576;             // [8192][64] = [H2_int | H2_nh]
    float* attp  = ws + 1572864;             // [32,6]
    float* out = (float*)d_out;

    k_dense_in<<<dim3(32, 2), 256, 0, stream>>>(x_int, x_nh, W1_int, W1_nh, P1T_0, P1T_1);
    // layer 1: F=16, 32 rows/block -> 256 blocks x 2 branches (2 blocks/CU)
    k_spmm<16><<<dim3(256, 2), 512, 0, stream>>>(adj_int, adj_nh, P1T_0, P1T_1,
                                                 b1_int, b1_nh, H1_0, H1_1, 16, 0);
    k_dense_mid<<<dim3(32, 2), 256, 0, stream>>>(H1_0, H1_1, W2_int, W2_nh, P2T_0, P2T_1);
    // layer 2: F=32, 16 rows/block -> 512 blocks x 2 branches; both branches
    // write into hcat ([.,0:32] int, [.,32:64] nh)
    k_spmm<32><<<dim3(512, 2), 512, 0, stream>>>(adj_int, adj_nh, P2T_0, P2T_1,
                                                 b2_int, b2_nh, hcat, hcat, 64, 32);
    k_att_pool<<<32, 256, 0, stream>>>(hcat, W_att, W_dense, attp);
    k_att_final<<<1, 64, 0, stream>>>(attp, b_dense, out);
}